// Round 1
// 410.223 us; speedup vs baseline: 1.1073x; 1.1073x over previous
//
#include <hip/hip_runtime.h>

#define HDIM 64
#define TDIM 512
#define WPB  4   // waves (batches) per block

// One wave (64 lanes) per batch element. All f32.
// Lane i owns h[i] and row i of W_hh in 16 float4 registers.
// Per timestep: h_new[i] = tanh(x_t*W_ih[i] + bias[i] + sum_j W_hh[i][j]*h[j])
//
// Round-3 change: the h[j] broadcast moves from v_readlane (65 VALU instrs,
// ~5 cy each -> ~320 of the 461 cy/timestep) to the LDS pipe:
//   - lane i publishes h[i] with one ds_write_b32
//   - all lanes read the same address -> HW broadcast, conflict-free,
//     16x ds_read_b128 fetches all 64 h values
//   - x_t broadcast via ds_read_b32 from an LDS-staged chunk (double-
//     buffered so the chunk-boundary overwrite can't serialize the pipe)
// LDS ops co-issue with VALU; write->read latency is hidden by the other
// 3 waves resident per SIMD. No barriers: per-wave private LDS slices.

__global__ __launch_bounds__(256, 4)   // cap VGPR at 128 so 4 waves/SIMD fit
void rnn_wave_per_batch_ldsb(const float* __restrict__ x,
                             const float* __restrict__ W_ih,
                             const float* __restrict__ W_hh,
                             const float* __restrict__ b_ih,
                             const float* __restrict__ b_hh,
                             const float* __restrict__ fc_w,
                             const float* __restrict__ fc_b,
                             float* __restrict__ out,
                             int B)
{
    __shared__ float hbuf[WPB][HDIM];      // per-wave h broadcast slot
    __shared__ float xbuf[WPB][2][64];     // per-wave x chunk, double-buffered

    const int lane  = threadIdx.x & 63;
    const int wid   = threadIdx.x >> 6;
    const int batch = blockIdx.x * WPB + wid;
    if (batch >= B) return;   // wave-uniform

    // --- W_hh row `lane` (64 f32 = 256 B contiguous) in 16 float4 regs ---
    const float4* wp = (const float4*)(W_hh + lane * HDIM);
    const float4 w0  = wp[0],  w1  = wp[1],  w2  = wp[2],  w3  = wp[3];
    const float4 w4  = wp[4],  w5  = wp[5],  w6  = wp[6],  w7  = wp[7];
    const float4 w8  = wp[8],  w9  = wp[9],  w10 = wp[10], w11 = wp[11];
    const float4 w12 = wp[12], w13 = wp[13], w14 = wp[14], w15 = wp[15];

    const float w_ih_l = W_ih[lane];                 // I == 1
    const float bias_l = b_ih[lane] + b_hh[lane];

    const float* xb = x + (size_t)batch * TDIM;      // x[batch][t], I==1
    float xc = xb[lane];                             // chunk 0 of x
    float h  = 0.0f;

    float*        hrow = hbuf[wid];
    const float4* hq   = (const float4*)hrow;

    const float TWO_LOG2E = 2.885390081777927f;      // 2*log2(e)

#define QUAD(W, q)                              \
    { float4 hv = hq[q];                        \
      a0 = fmaf(W.x, hv.x, a0);                 \
      a1 = fmaf(W.y, hv.y, a1);                 \
      a2 = fmaf(W.z, hv.z, a2);                 \
      a3 = fmaf(W.w, hv.w, a3); }

    for (int c = 0; c < TDIM / 64; ++c) {
        // stage this chunk's 64 x values in LDS (write buf c&1),
        // then prefetch the next chunk from global (coalesced 256B/wave)
        xbuf[wid][c & 1][lane] = xc;
        if (c + 1 < TDIM / 64)
            xc = xb[(c + 1) * 64 + lane];
        const float* xr = xbuf[wid][c & 1];

#pragma unroll 1   // keep body small; fits I$
        for (int j = 0; j < 64; ++j) {
            hrow[lane] = h;                      // ds_write_b32: publish h[i]
            float xt = xr[j];                    // ds_read_b32 broadcast (uniform addr)

            float a0 = fmaf(xt, w_ih_l, bias_l);
            float a1 = 0.f, a2 = 0.f, a3 = 0.f;
            QUAD(w0,   0)  QUAD(w1,   1)  QUAD(w2,   2)  QUAD(w3,   3)
            QUAD(w4,   4)  QUAD(w5,   5)  QUAD(w6,   6)  QUAD(w7,   7)
            QUAD(w8,   8)  QUAD(w9,   9)  QUAD(w10, 10)  QUAD(w11, 11)
            QUAD(w12, 12)  QUAD(w13, 13)  QUAD(w14, 14)  QUAD(w15, 15)
            float z = (a0 + a1) + (a2 + a3);
            // tanh(z) = 1 - 2/(1 + e^{2z}); saturates correctly for large |z|
            float t = __builtin_amdgcn_exp2f(z * TWO_LOG2E);
            float r = __builtin_amdgcn_rcpf(t + 1.0f);
            h = fmaf(-2.0f, r, 1.0f);
        }
    }
#undef QUAD

    // out[batch] = sum_i h[i]*fc_w[i] + fc_b   (wave-wide butterfly reduce)
    float v = h * fc_w[lane];
#pragma unroll
    for (int off = 32; off > 0; off >>= 1)
        v += __shfl_xor(v, off, 64);

    if (lane == 0)
        out[batch] = v + fc_b[0];
}

extern "C" void kernel_launch(void* const* d_in, const int* in_sizes, int n_in,
                              void* d_out, int out_size, void* d_ws, size_t ws_size,
                              hipStream_t stream)
{
    const float* x    = (const float*)d_in[0];
    const float* W_ih = (const float*)d_in[1];
    const float* W_hh = (const float*)d_in[2];
    const float* b_ih = (const float*)d_in[3];
    const float* b_hh = (const float*)d_in[4];
    const float* fc_w = (const float*)d_in[5];
    const float* fc_b = (const float*)d_in[6];
    float* out = (float*)d_out;

    const int B = in_sizes[0] / TDIM;          // x is (B, T, 1)
    const int blocks = (B + WPB - 1) / WPB;

    rnn_wave_per_batch_ldsb<<<blocks, WPB * 64, 0, stream>>>(
        x, W_ih, W_hh, b_ih, b_hh, fc_w, fc_b, out, B);
}